// Round 7
// baseline (314.178 us; speedup 1.0000x reference)
//
#include <hip/hip_runtime.h>
#include <hip/hip_bf16.h>

#define S_LEN 2048
#define NHQ 32
#define NHKV 8
#define DH 128
#define KTILE 32
#define KS_PITCH 136   // ushorts; row stride 272B
#define VT_PITCH 40    // ushorts; row stride 80B = 20 dwords -> b128 R/W uniform banks
#define PS_PITCH 40
#define KV_STRIDE ((size_t)NHKV * DH)

typedef float f32x4 __attribute__((ext_vector_type(4)));
typedef short bf16x8 __attribute__((ext_vector_type(8)));
typedef float float4_t __attribute__((ext_vector_type(4)));

__device__ __forceinline__ unsigned short f2bf(float f) {
  union { __hip_bfloat16 h; unsigned short u; } c;
  c.h = __float2bfloat16(f);
  return c.u;
}

__device__ __forceinline__ bf16x8 pack8(float4_t a, float4_t b) {
  bf16x8 f;
  f[0] = (short)f2bf(a[0]); f[1] = (short)f2bf(a[1]);
  f[2] = (short)f2bf(a[2]); f[3] = (short)f2bf(a[3]);
  f[4] = (short)f2bf(b[0]); f[5] = (short)f2bf(b[1]);
  f[6] = (short)f2bf(b[2]); f[7] = (short)f2bf(b[3]);
  return f;
}

// 512 threads = 8 waves: wave w handles 16 q-rows (row-group w>>2) of head (w&3).
// Same K/V staging per block as the 4-wave version -> 2x waves/CU at equal work.
__global__ __launch_bounds__(512, 4) void attn_fwd(
    const float* __restrict__ Q, const float* __restrict__ K,
    const float* __restrict__ V, float* __restrict__ O) {
  __shared__ unsigned short Ks[2][KTILE * KS_PITCH];  // double-buffered K tile
  __shared__ unsigned short Vt[2][DH * VT_PITCH];     // double-buffered V^T tile
  __shared__ unsigned short Ps[8][16 * PS_PITCH];     // per-wave P (16 q-rows)

  const int bid = blockIdx.x;
  const int kvh = bid & 7;            // XCD-locality: one KV-head per XCD
  // Complementary pairing: one early-half + one late-half block per CU.
  const int qt = (bid < 256) ? (63 - (bid >> 3)) : ((bid - 256) >> 3);
  const int q0 = qt * 32;
  const int tid = threadIdx.x;
  const int wid = tid >> 6;           // 0..7
  const int hq = wid & 3;             // head within GQA group
  const int rg = wid >> 2;            // row-group (0: rows 0-15, 1: rows 16-31)
  const int lane = tid & 63;
  const int l15 = lane & 15;
  const int l4 = lane >> 4;
  const int h = kvh * 4 + hq;

  // scale * log2(e), folded into Q at pack time (softmax in exp2 domain)
  const float kscale = 0.08838834764831845f * 1.44269504088896340f;

  // ---- hoist Q (pre-scaled): A-frag row=l&15, k=(l>>4)*8+j ----
  bf16x8 qf[4];
  {
    const float* qp = Q + ((size_t)(q0 + rg * 16 + l15) * NHQ + h) * DH;
#pragma unroll
    for (int dc = 0; dc < 4; ++dc) {
      float4_t a = *(const float4_t*)(qp + dc * 32 + l4 * 8);
      float4_t b = *(const float4_t*)(qp + dc * 32 + l4 * 8 + 4);
      a *= kscale;
      b *= kscale;
      qf[dc] = pack8(a, b);
    }
  }

  f32x4 o[8];
#pragma unroll
  for (int dt = 0; dt < 8; ++dt) o[dt] = (f32x4){0.f, 0.f, 0.f, 0.f};
  float mrow[4] = {-1e30f, -1e30f, -1e30f, -1e30f};
  float lrow[4] = {0.f, 0.f, 0.f, 0.f};

  // staging roles (512 threads)
  const int krow = tid >> 4;          // 0..31
  const int kcol = (tid & 15) * 8;    // 0..120
  const float* kbase = K + ((size_t)krow * NHKV + kvh) * DH + kcol;
  const int vd = tid & 127;           // thread owns one d
  const int vk0 = (tid >> 7) * 8;     // 8 keys: vk0..vk0+7
  const float* vbase = V + ((size_t)vk0 * NHKV + kvh) * DH + vd;

  // in-flight tile: named registers only (no arrays -> no scratch)
  float4_t kr0, kr1;                  // K row krow, 8 floats
  float4_t vr0, vr1;                  // V d=vd, keys vk0..vk0+7

  auto load_tile = [&](int kv0) {
    const float* kp = kbase + (size_t)kv0 * KV_STRIDE;
    kr0 = *(const float4_t*)kp;
    kr1 = *(const float4_t*)(kp + 4);
    const float* vp = vbase + (size_t)kv0 * KV_STRIDE;
    vr0 = (float4_t){vp[0 * KV_STRIDE], vp[1 * KV_STRIDE], vp[2 * KV_STRIDE], vp[3 * KV_STRIDE]};
    vr1 = (float4_t){vp[4 * KV_STRIDE], vp[5 * KV_STRIDE], vp[6 * KV_STRIDE], vp[7 * KV_STRIDE]};
  };
  auto store_tile = [&](int buf) {
    *(bf16x8*)&Ks[buf][krow * KS_PITCH + kcol] = pack8(kr0, kr1);
    *(bf16x8*)&Vt[buf][vd * VT_PITCH + vk0] = pack8(vr0, vr1);
  };

  // prologue: stage tile 0 into buf 0
  load_tile(0);
  store_tile(0);
  __syncthreads();

  const int ntile = qt + 1;  // causal: keys 0 .. q0+31
  for (int t = 0; t < ntile; ++t) {
    const int cur = t & 1;
    const bool pf = (t + 1 < ntile);
    if (pf) load_tile((t + 1) * KTILE);  // issue early: hides under compute

    // ---- S = Q K^T on buf[cur]: 16 rows x 32 keys ----
    const unsigned short* KsC = Ks[cur];
    f32x4 s0 = (f32x4){0.f, 0.f, 0.f, 0.f};
    f32x4 s1 = (f32x4){0.f, 0.f, 0.f, 0.f};
#pragma unroll
    for (int dc = 0; dc < 4; ++dc) {
      bf16x8 k0 = *(const bf16x8*)&KsC[l15 * KS_PITCH + dc * 32 + l4 * 8];
      bf16x8 k1 = *(const bf16x8*)&KsC[(16 + l15) * KS_PITCH + dc * 32 + l4 * 8];
      s0 = __builtin_amdgcn_mfma_f32_16x16x32_bf16(qf[dc], k0, s0, 0, 0, 0);
      s1 = __builtin_amdgcn_mfma_f32_16x16x32_bf16(qf[dc], k1, s1, 0, 0, 0);
    }

    // ---- softmax pass 1: mask + row max ----
    const bool needmask = (t == qt);
    float tv0[4], tv1[4], mxr[4];
#pragma unroll
    for (int r = 0; r < 4; ++r) {
      float t0 = s0[r];
      float t1 = s1[r];
      if (needmask) {
        int qg = rg * 16 + l4 * 4 + r;  // row within band; diag tile: kv0 == q0
        if (l15 > qg) t0 = -1e30f;
        if (16 + l15 > qg) t1 = -1e30f;
      }
      float mx = fmaxf(t0, t1);
      mx = fmaxf(mx, __shfl_xor(mx, 1, 16));
      mx = fmaxf(mx, __shfl_xor(mx, 2, 16));
      mx = fmaxf(mx, __shfl_xor(mx, 4, 16));
      mx = fmaxf(mx, __shfl_xor(mx, 8, 16));
      tv0[r] = t0; tv1[r] = t1; mxr[r] = mx;
    }

    // ---- defer-max: wave-uniform skip of the O-rescale (THR=8 in exp2 dom) ----
    bool small = true;
#pragma unroll
    for (int r = 0; r < 4; ++r) small &= (mxr[r] <= mrow[r] + 8.0f);
    const bool skiprs = __all((int)small);

    if (skiprs) {
#pragma unroll
      for (int r = 0; r < 4; ++r) {
        float p0 = __builtin_amdgcn_exp2f(tv0[r] - mrow[r]);
        float p1 = __builtin_amdgcn_exp2f(tv1[r] - mrow[r]);
        lrow[r] += p0 + p1;
        unsigned short* pw = &Ps[wid][(l4 * 4 + r) * PS_PITCH];
        pw[l15] = f2bf(p0);
        pw[16 + l15] = f2bf(p1);
      }
    } else {
#pragma unroll
      for (int r = 0; r < 4; ++r) {
        float mn = fmaxf(mrow[r], mxr[r]);
        float al = __builtin_amdgcn_exp2f(mrow[r] - mn);
        float p0 = __builtin_amdgcn_exp2f(tv0[r] - mn);
        float p1 = __builtin_amdgcn_exp2f(tv1[r] - mn);
        mrow[r] = mn;
        lrow[r] = lrow[r] * al + p0 + p1;
#pragma unroll
        for (int dt = 0; dt < 8; ++dt) o[dt][r] *= al;
        unsigned short* pw = &Ps[wid][(l4 * 4 + r) * PS_PITCH];
        pw[l15] = f2bf(p0);
        pw[16 + l15] = f2bf(p1);
      }
    }

    // ---- O += P V on buf[cur] ----
    const unsigned short* VtC = Vt[cur];
    bf16x8 pa = *(const bf16x8*)&Ps[wid][l15 * PS_PITCH + l4 * 8];
#pragma unroll
    for (int dt = 0; dt < 8; ++dt) {
      bf16x8 bv = *(const bf16x8*)&VtC[(dt * 16 + l15) * VT_PITCH + l4 * 8];
      o[dt] = __builtin_amdgcn_mfma_f32_16x16x32_bf16(pa, bv, o[dt], 0, 0, 0);
    }

    // ---- write next tile into the other buffer; single barrier per tile ----
    if (pf) store_tile(cur ^ 1);
    __syncthreads();
  }

  // ---- epilogue: reduce row sums, normalize, store fp32 ----
#pragma unroll
  for (int r = 0; r < 4; ++r) {
    float ssum = lrow[r];
    ssum += __shfl_xor(ssum, 1, 16);
    ssum += __shfl_xor(ssum, 2, 16);
    ssum += __shfl_xor(ssum, 4, 16);
    ssum += __shfl_xor(ssum, 8, 16);
    float inv = 1.0f / ssum;
    int qg = q0 + rg * 16 + l4 * 4 + r;
    float* op = O + ((size_t)qg * NHQ + h) * DH;
#pragma unroll
    for (int dt = 0; dt < 8; ++dt) op[dt * 16 + l15] = o[dt][r] * inv;
  }
}

extern "C" void kernel_launch(void* const* d_in, const int* in_sizes, int n_in,
                              void* d_out, int out_size, void* d_ws, size_t ws_size,
                              hipStream_t stream) {
  const float* Q = (const float*)d_in[0];
  const float* K = (const float*)d_in[1];
  const float* V = (const float*)d_in[2];
  float* O = (float*)d_out;
  attn_fwd<<<dim3((S_LEN / 32) * NHKV), dim3(512), 0, stream>>>(Q, K, V, O);
}

// Round 8
// 209.444 us; speedup vs baseline: 1.5001x; 1.5001x over previous
//
#include <hip/hip_runtime.h>
#include <hip/hip_bf16.h>

#define S_LEN 2048
#define NHQ 32
#define NHKV 8
#define DH 128
#define KTILE 32
#define KS_PITCH 136   // ushorts; row stride 272B
#define VT_PITCH 40    // ushorts; row stride 80B = 20 dwords -> b128 R/W uniform banks
#define PS_PITCH 40
#define KV_STRIDE ((size_t)NHKV * DH)

typedef float f32x4 __attribute__((ext_vector_type(4)));
typedef short bf16x8 __attribute__((ext_vector_type(8)));
typedef float float4_t __attribute__((ext_vector_type(4)));

__device__ __forceinline__ unsigned short f2bf(float f) {
  union { __hip_bfloat16 h; unsigned short u; } c;
  c.h = __float2bfloat16(f);
  return c.u;
}

__device__ __forceinline__ bf16x8 pack8(float4_t a, float4_t b) {
  bf16x8 f;
  f[0] = (short)f2bf(a[0]); f[1] = (short)f2bf(a[1]);
  f[2] = (short)f2bf(a[2]); f[3] = (short)f2bf(a[3]);
  f[4] = (short)f2bf(b[0]); f[5] = (short)f2bf(b[1]);
  f[6] = (short)f2bf(b[2]); f[7] = (short)f2bf(b[3]);
  return f;
}

// 512 threads = 8 waves: wave w handles 16 q-rows (row-group w>>2) of head (w&3).
// launch_bounds(512,2): empirically the 2nd arg scales like blocks/CU for
// 512-thread blocks -> 2 blocks/CU = 16 waves/CU = 4 waves/SIMD, VGPR cap 128.
// (512,4) forced a 64-VGPR cap and catastrophic scratch spill (R7: 163MB writes).
__global__ __launch_bounds__(512, 2) void attn_fwd(
    const float* __restrict__ Q, const float* __restrict__ K,
    const float* __restrict__ V, float* __restrict__ O) {
  __shared__ unsigned short Ks[2][KTILE * KS_PITCH];  // double-buffered K tile
  __shared__ unsigned short Vt[2][DH * VT_PITCH];     // double-buffered V^T tile
  __shared__ unsigned short Ps[8][16 * PS_PITCH];     // per-wave P (16 q-rows)

  const int bid = blockIdx.x;
  const int kvh = bid & 7;            // XCD-locality: one KV-head per XCD
  // Complementary pairing: one early-half + one late-half block per CU.
  const int qt = (bid < 256) ? (63 - (bid >> 3)) : ((bid - 256) >> 3);
  const int q0 = qt * 32;
  const int tid = threadIdx.x;
  const int wid = tid >> 6;           // 0..7
  const int hq = wid & 3;             // head within GQA group
  const int rg = wid >> 2;            // row-group (0: rows 0-15, 1: rows 16-31)
  const int lane = tid & 63;
  const int l15 = lane & 15;
  const int l4 = lane >> 4;
  const int h = kvh * 4 + hq;

  // scale * log2(e), folded into Q at pack time (softmax in exp2 domain)
  const float kscale = 0.08838834764831845f * 1.44269504088896340f;

  // ---- hoist Q (pre-scaled): A-frag row=l&15, k=(l>>4)*8+j ----
  bf16x8 qf[4];
  {
    const float* qp = Q + ((size_t)(q0 + rg * 16 + l15) * NHQ + h) * DH;
#pragma unroll
    for (int dc = 0; dc < 4; ++dc) {
      float4_t a = *(const float4_t*)(qp + dc * 32 + l4 * 8);
      float4_t b = *(const float4_t*)(qp + dc * 32 + l4 * 8 + 4);
      a *= kscale;
      b *= kscale;
      qf[dc] = pack8(a, b);
    }
  }

  f32x4 o[8];
#pragma unroll
  for (int dt = 0; dt < 8; ++dt) o[dt] = (f32x4){0.f, 0.f, 0.f, 0.f};
  float mrow[4] = {-1e30f, -1e30f, -1e30f, -1e30f};
  float lrow[4] = {0.f, 0.f, 0.f, 0.f};

  // staging roles (512 threads)
  const int krow = tid >> 4;          // 0..31
  const int kcol = (tid & 15) * 8;    // 0..120
  const float* kbase = K + ((size_t)krow * NHKV + kvh) * DH + kcol;
  const int vd = tid & 127;           // thread owns one d
  const int vk0 = (tid >> 7) * 8;     // 8 keys: vk0..vk0+7
  const float* vbase = V + ((size_t)vk0 * NHKV + kvh) * DH + vd;

  // in-flight tile: named registers only (no arrays -> no scratch)
  float4_t kr0, kr1;                  // K row krow, 8 floats
  float4_t vr0, vr1;                  // V d=vd, keys vk0..vk0+7

  auto load_tile = [&](int kv0) {
    const float* kp = kbase + (size_t)kv0 * KV_STRIDE;
    kr0 = *(const float4_t*)kp;
    kr1 = *(const float4_t*)(kp + 4);
    const float* vp = vbase + (size_t)kv0 * KV_STRIDE;
    vr0 = (float4_t){vp[0 * KV_STRIDE], vp[1 * KV_STRIDE], vp[2 * KV_STRIDE], vp[3 * KV_STRIDE]};
    vr1 = (float4_t){vp[4 * KV_STRIDE], vp[5 * KV_STRIDE], vp[6 * KV_STRIDE], vp[7 * KV_STRIDE]};
  };
  auto store_tile = [&](int buf) {
    *(bf16x8*)&Ks[buf][krow * KS_PITCH + kcol] = pack8(kr0, kr1);
    *(bf16x8*)&Vt[buf][vd * VT_PITCH + vk0] = pack8(vr0, vr1);
  };

  // prologue: stage tile 0 into buf 0
  load_tile(0);
  store_tile(0);
  __syncthreads();

  const int ntile = qt + 1;  // causal: keys 0 .. q0+31
  for (int t = 0; t < ntile; ++t) {
    const int cur = t & 1;
    const bool pf = (t + 1 < ntile);
    if (pf) load_tile((t + 1) * KTILE);  // issue early: hides under compute

    // ---- S = Q K^T on buf[cur]: 16 rows x 32 keys ----
    const unsigned short* KsC = Ks[cur];
    f32x4 s0 = (f32x4){0.f, 0.f, 0.f, 0.f};
    f32x4 s1 = (f32x4){0.f, 0.f, 0.f, 0.f};
#pragma unroll
    for (int dc = 0; dc < 4; ++dc) {
      bf16x8 k0 = *(const bf16x8*)&KsC[l15 * KS_PITCH + dc * 32 + l4 * 8];
      bf16x8 k1 = *(const bf16x8*)&KsC[(16 + l15) * KS_PITCH + dc * 32 + l4 * 8];
      s0 = __builtin_amdgcn_mfma_f32_16x16x32_bf16(qf[dc], k0, s0, 0, 0, 0);
      s1 = __builtin_amdgcn_mfma_f32_16x16x32_bf16(qf[dc], k1, s1, 0, 0, 0);
    }

    // ---- softmax pass 1: mask IN-PLACE + row max (minimize live state) ----
    const bool needmask = (t == qt);
    float mxr[4];
#pragma unroll
    for (int r = 0; r < 4; ++r) {
      if (needmask) {
        int qg = rg * 16 + l4 * 4 + r;  // diag tile: kv0 == q0
        if (l15 > qg) s0[r] = -1e30f;
        if (16 + l15 > qg) s1[r] = -1e30f;
      }
      float mx = fmaxf(s0[r], s1[r]);
      mx = fmaxf(mx, __shfl_xor(mx, 1, 16));
      mx = fmaxf(mx, __shfl_xor(mx, 2, 16));
      mx = fmaxf(mx, __shfl_xor(mx, 4, 16));
      mx = fmaxf(mx, __shfl_xor(mx, 8, 16));
      mxr[r] = mx;
    }

    // ---- defer-max: wave-uniform skip of the O-rescale (THR=8 in exp2 dom) ----
    bool small = true;
#pragma unroll
    for (int r = 0; r < 4; ++r) small &= (mxr[r] <= mrow[r] + 8.0f);
    const bool skiprs = __all((int)small);

    if (skiprs) {
#pragma unroll
      for (int r = 0; r < 4; ++r) {
        float p0 = __builtin_amdgcn_exp2f(s0[r] - mrow[r]);
        float p1 = __builtin_amdgcn_exp2f(s1[r] - mrow[r]);
        lrow[r] += p0 + p1;
        unsigned short* pw = &Ps[wid][(l4 * 4 + r) * PS_PITCH];
        pw[l15] = f2bf(p0);
        pw[16 + l15] = f2bf(p1);
      }
    } else {
#pragma unroll
      for (int r = 0; r < 4; ++r) {
        float mn = fmaxf(mrow[r], mxr[r]);
        float al = __builtin_amdgcn_exp2f(mrow[r] - mn);
        float p0 = __builtin_amdgcn_exp2f(s0[r] - mn);
        float p1 = __builtin_amdgcn_exp2f(s1[r] - mn);
        mrow[r] = mn;
        lrow[r] = lrow[r] * al + p0 + p1;
#pragma unroll
        for (int dt = 0; dt < 8; ++dt) o[dt][r] *= al;
        unsigned short* pw = &Ps[wid][(l4 * 4 + r) * PS_PITCH];
        pw[l15] = f2bf(p0);
        pw[16 + l15] = f2bf(p1);
      }
    }

    // ---- O += P V on buf[cur] ----
    const unsigned short* VtC = Vt[cur];
    bf16x8 pa = *(const bf16x8*)&Ps[wid][l15 * PS_PITCH + l4 * 8];
#pragma unroll
    for (int dt = 0; dt < 8; ++dt) {
      bf16x8 bv = *(const bf16x8*)&VtC[(dt * 16 + l15) * VT_PITCH + l4 * 8];
      o[dt] = __builtin_amdgcn_mfma_f32_16x16x32_bf16(pa, bv, o[dt], 0, 0, 0);
    }

    // ---- write next tile into the other buffer; single barrier per tile ----
    if (pf) store_tile(cur ^ 1);
    __syncthreads();
  }

  // ---- epilogue: reduce row sums, normalize, store fp32 ----
#pragma unroll
  for (int r = 0; r < 4; ++r) {
    float ssum = lrow[r];
    ssum += __shfl_xor(ssum, 1, 16);
    ssum += __shfl_xor(ssum, 2, 16);
    ssum += __shfl_xor(ssum, 4, 16);
    ssum += __shfl_xor(ssum, 8, 16);
    float inv = 1.0f / ssum;
    int qg = q0 + rg * 16 + l4 * 4 + r;
    float* op = O + ((size_t)qg * NHQ + h) * DH;
#pragma unroll
    for (int dt = 0; dt < 8; ++dt) op[dt * 16 + l15] = o[dt][r] * inv;
  }
}

extern "C" void kernel_launch(void* const* d_in, const int* in_sizes, int n_in,
                              void* d_out, int out_size, void* d_ws, size_t ws_size,
                              hipStream_t stream) {
  const float* Q = (const float*)d_in[0];
  const float* K = (const float*)d_in[1];
  const float* V = (const float*)d_in[2];
  float* O = (float*)d_out;
  attn_fwd<<<dim3((S_LEN / 32) * NHKV), dim3(512), 0, stream>>>(Q, K, V, O);
}